// Round 9
// baseline (387.799 us; speedup 1.0000x reference)
//
#include <hip/hip_runtime.h>
#include <hip/hip_bf16.h>
#include <cstdint>
#include <cstddef>

typedef __attribute__((ext_vector_type(8))) short short8;
typedef __attribute__((ext_vector_type(4))) float floatx4;

// V=1024 C=8 T=256 BP=4 K=512 E=128 D=128 NB=24 NH=4 HD=32 FF=512 R=8 B=32

__device__ __forceinline__ ushort f2bf(float f) {
    union { float f; unsigned int u; } x; x.f = f;
    unsigned int r = (x.u + 0x7fffu + ((x.u >> 16) & 1u)) >> 16;
    return (ushort)r;
}
__device__ __forceinline__ float bf2f(ushort u) {
    union { unsigned int u; float f; } x; x.u = ((unsigned int)u) << 16;
    return x.f;
}

// ---------------- single merged prep kernel ----------------
__global__ __launch_bounds__(256) void prep_all(
    const float* __restrict__ emb, const float* __restrict__ w1,
    const float* __restrict__ w2, const float* __restrict__ cbi,
    const float* __restrict__ cbv, const float* __restrict__ aiw,
    const float* __restrict__ aow, const float* __restrict__ l1w,
    const float* __restrict__ l2w,
    ushort* __restrict__ ebf, ushort* __restrict__ w1bf, ushort* __restrict__ w2bf,
    float* __restrict__ cbiT, float* __restrict__ cbvT,
    ushort* __restrict__ aiwbf, ushort* __restrict__ aowbf,
    ushort* __restrict__ l1wbf, ushort* __restrict__ l2wbf,
    float* __restrict__ accum)
{
    int idx = blockIdx.x * 256 + threadIdx.x;
    if (idx < 16) accum[idx] = 0.f;
    if (idx < 131072) {
        ebf[idx] = f2bf(emb[idx]);
    } else if (idx < 262144) {
        int j = idx - 131072; w2bf[j] = f2bf(w2[j]);
    } else if (idx < 327680) {
        int j = idx - 262144; cbiT[(j & 127) * 512 + (j >> 7)] = cbi[j];
    } else if (idx < 393216) {
        int j = idx - 327680; cbvT[(j & 127) * 512 + (j >> 7)] = cbv[j];
    } else if (idx < 442368) {
        int j = idx - 393216; aiwbf[j] = f2bf(aiw[j]);
    } else if (idx < 475136) {
        int j = idx - 442368; aowbf[j] = f2bf(aow[j]);
    } else if (idx < 540672) {
        int j = idx - 475136; l1wbf[j] = f2bf(l1w[j]);
    } else if (idx < 606208) {
        int j = idx - 540672; l2wbf[j] = f2bf(l2w[j]);
    } else if (idx < 1130496) {
        int j = idx - 606208;            // (co*8+cc)*128+e, all 3 kw per thread
        int e  = j & 127;
        int cc = (j >> 7) & 7;
        int co = j >> 10;
        const float* src = w1 + ((size_t)co * 1024 + cc * 128 + e) * 3;
        float v0 = src[0], v1 = src[1], v2 = src[2];
        w1bf[((size_t)(0 * 8 + cc) * 512 + co) * 128 + e] = f2bf(v0);
        w1bf[((size_t)(1 * 8 + cc) * 512 + co) * 128 + e] = f2bf(v1);
        w1bf[((size_t)(2 * 8 + cc) * 512 + co) * 128 + e] = f2bf(v2);
    }
}

// ---------------- conv1: implicit GEMM, 64x128 tile, 3 blocks/CU, reg tokens ----------------
// grid 1536 = 384 m-tiles x 4 n-tiles; 512 threads = 8 waves (2m x 4n)
__global__ __launch_bounds__(512, 6) void conv1_mfma(
    const int* __restrict__ tp, const int* __restrict__ tcu, const int* __restrict__ tn,
    const ushort* __restrict__ ebf, const ushort* __restrict__ w1bf,
    const float* __restrict__ b1, ushort* __restrict__ y1)
{
    constexpr int LDA = 136;
    __shared__ ushort As[66 * LDA];    // t0-1 .. t0+64 (halo), e 0..127
    __shared__ ushort Bs[128 * LDA];
    const int tid = threadIdx.x;
    const int bx = blockIdx.x;
    const int nb = bx & 3, mb = bx >> 2;
    const int set = mb >> 7, bb = (mb >> 2) & 31, t0 = (mb & 3) << 6;
    const int n0 = nb << 7;
    const int* tok = (set == 0) ? tp : ((set == 1) ? tcu : tn);

    const int w = tid >> 6, lane = tid & 63;
    const int wm = w & 1, wn = w >> 1;          // 2 m-groups x 4 n-groups
    const int rA = lane & 15, q4 = lane >> 4;
    const int ch = tid & 15, rowst = tid >> 4;  // 32 rows per staging pass

    // preload this thread's 24 token indices into registers (no LDS, no dep chain)
    int tokr[3][8];
    for (int p = 0; p < 3; ++p) {
        const int row = p * 32 + rowst;
        const int gt = t0 + row - 1;
        const bool ok = (row < 66) && (gt >= 0) && (gt < 256);
        for (int cc = 0; cc < 8; ++cc)
            tokr[p][cc] = ok ? tok[bb * 2048 + gt * 8 + cc] : -1;
    }

    floatx4 acc[2][2];
    for (int mi = 0; mi < 2; ++mi)
        for (int ni = 0; ni < 2; ++ni)
            acc[mi][ni] = (floatx4)(0.0f);

    for (int cc = 0; cc < 8; ++cc) {
        // stage A (66 rows, reused by all 3 kw)
        for (int p = 0; p < 3; ++p) {
            const int row = p * 32 + rowst;
            if (row < 66) {
                const int tk = tokr[p][cc];
                uint4 val = make_uint4(0u, 0u, 0u, 0u);
                if (tk >= 0) val = *(const uint4*)(ebf + tk * 128 + ch * 8);
                *(uint4*)(As + row * LDA + ch * 8) = val;
            }
        }
        for (int kw = 0; kw < 3; ++kw) {
            const ushort* wsrc = w1bf + ((size_t)((kw * 8 + cc) * 512 + n0)) * 128;
            for (int p = 0; p < 4; ++p) {
                const int row = p * 32 + rowst;
                *(uint4*)(Bs + row * LDA + ch * 8) = *(const uint4*)(wsrc + row * 128 + ch * 8);
            }
            __syncthreads();
            for (int ks = 0; ks < 4; ++ks) {
                const int k0 = ks * 32 + q4 * 8;
                short8 a[2], bfr[2];
                for (int mi = 0; mi < 2; ++mi)
                    a[mi] = *(const short8*)(As + (wm * 32 + mi * 16 + rA + kw) * LDA + k0);
                for (int ni = 0; ni < 2; ++ni)
                    bfr[ni] = *(const short8*)(Bs + (wn * 32 + ni * 16 + rA) * LDA + k0);
                for (int mi = 0; mi < 2; ++mi)
                    for (int ni = 0; ni < 2; ++ni)
                        acc[mi][ni] = __builtin_amdgcn_mfma_f32_16x16x32_bf16(
                            a[mi], bfr[ni], acc[mi][ni], 0, 0, 0);
            }
            __syncthreads();
        }
    }
    for (int ni = 0; ni < 2; ++ni) {
        const int co = n0 + wn * 32 + ni * 16 + rA;
        const float bias = b1[co];
        for (int mi = 0; mi < 2; ++mi) {
            for (int r = 0; r < 4; ++r) {
                const int t = t0 + wm * 32 + mi * 16 + q4 * 4 + r;
                float v = acc[mi][ni][r] + bias;
                v = v > 0.f ? v : 0.f;
                y1[((size_t)(set * 32 + bb) * 256 + t) * 512 + co] = f2bf(v);
            }
        }
    }
}

// ---------------- conv2 + avgpool(64): 128x128 tile ----------------
__global__ __launch_bounds__(512, 4) void conv2_mfma(
    const ushort* __restrict__ y1, const ushort* __restrict__ w2bf,
    const float* __restrict__ b2, float* __restrict__ y2)
{
    constexpr int LDA = 136;
    __shared__ ushort As[128 * LDA];
    __shared__ ushort Bs[128 * LDA];
    __shared__ float pool[256];
    const int tid = threadIdx.x;
    const int bx = blockIdx.x;
    const int nb = bx & 1, mb = bx >> 1;
    const int set = mb >> 6, rem = mb & 63, bb = rem >> 1, t0 = (rem & 1) << 7;
    const int n0 = nb << 7;
    const int w = tid >> 6, lane = tid & 63;
    const int wm = w & 1, wn = w >> 1;
    const int rA = lane & 15, q4 = lane >> 4;
    const int ch = tid & 15, rowst = tid >> 4;

    floatx4 acc[4][2];
    for (int mi = 0; mi < 4; ++mi)
        for (int ni = 0; ni < 2; ++ni)
            acc[mi][ni] = (floatx4)(0.0f);

    const size_t arowbase = ((size_t)(set * 32 + bb) * 256 + t0) * 512;
    for (int kc = 0; kc < 4; ++kc) {
        for (int p = 0; p < 4; ++p) {
            const int row = p * 32 + rowst;
            *(uint4*)(As + row * LDA + ch * 8) =
                *(const uint4*)(y1 + arowbase + (size_t)row * 512 + kc * 128 + ch * 8);
            *(uint4*)(Bs + row * LDA + ch * 8) =
                *(const uint4*)(w2bf + (size_t)(n0 + row) * 512 + kc * 128 + ch * 8);
        }
        __syncthreads();
        for (int ks = 0; ks < 4; ++ks) {
            const int k0 = ks * 32 + q4 * 8;
            short8 a[4], bfr[2];
            for (int mi = 0; mi < 4; ++mi)
                a[mi] = *(const short8*)(As + (wm * 64 + mi * 16 + rA) * LDA + k0);
            for (int ni = 0; ni < 2; ++ni)
                bfr[ni] = *(const short8*)(Bs + (wn * 32 + ni * 16 + rA) * LDA + k0);
            for (int mi = 0; mi < 4; ++mi)
                for (int ni = 0; ni < 2; ++ni)
                    acc[mi][ni] = __builtin_amdgcn_mfma_f32_16x16x32_bf16(
                        a[mi], bfr[ni], acc[mi][ni], 0, 0, 0);
        }
        __syncthreads();
    }
    for (int ni = 0; ni < 2; ++ni) {
        const int col = wn * 32 + ni * 16 + rA;
        const float bias = b2[n0 + col];
        float s = 0.f;
        for (int mi = 0; mi < 4; ++mi)
            for (int r = 0; r < 4; ++r) {
                float v = acc[mi][ni][r] + bias;
                s += v > 0.f ? v : 0.f;
            }
        s += __shfl_xor(s, 16);
        s += __shfl_xor(s, 32);
        if (q4 == 0) pool[wm * 128 + col] = s;
    }
    __syncthreads();
    if (tid < 256) {
        const int wrow = tid >> 7, col = tid & 127;
        const int p = (t0 >> 6) + wrow;
        y2[((size_t)(set * 32 + bb) * 4 + p) * 256 + n0 + col] = pool[tid] * (1.f / 64.f);
    }
}

// ---------------- VQ ----------------
__global__ __launch_bounds__(256) void vq_kernel(
    const float* __restrict__ y2, const float* __restrict__ cbiT, const float* __restrict__ cbvT,
    const float* __restrict__ cbi, const float* __restrict__ cbv,
    const float* __restrict__ pos, float* __restrict__ ztr, float* __restrict__ accum)
{
    const int q = blockIdx.x;
    const int tid = threadIdx.x;
    const int set = q >> 7, bb = (q >> 2) & 31, p = q & 3;
    __shared__ float zloc[256];
    __shared__ float bestv[4];
    __shared__ int   besti[4];
    __shared__ int   code_sh[2];
    __shared__ float wsum2[4];
    zloc[tid] = y2[(size_t)q * 256 + tid];
    __syncthreads();
    const int w = tid >> 6, lane = tid & 63;
    const int half = w >> 1, sub = w & 1;
    const float4* cbT4 = (const float4*)(half ? cbvT : cbiT);
    const float* zh = zloc + half * 128;
    const int k4 = sub * 64 + lane;
    float a0 = 0.f, a1 = 0.f, a2 = 0.f, a3 = 0.f;
    for (int d = 0; d < 128; ++d) {
        float4 v = cbT4[d * 128 + k4];
        const float z = zh[d];
        float d0 = z - v.x, d1 = z - v.y, d2 = z - v.z, d3 = z - v.w;
        a0 += d0 * d0; a1 += d1 * d1; a2 += d2 * d2; a3 += d3 * d3;
    }
    float best = a0; int bidx = k4 * 4;
    if (a1 < best) { best = a1; bidx = k4 * 4 + 1; }
    if (a2 < best) { best = a2; bidx = k4 * 4 + 2; }
    if (a3 < best) { best = a3; bidx = k4 * 4 + 3; }
    for (int off = 32; off > 0; off >>= 1) {
        float ov = __shfl_xor(best, off);
        int   oi = __shfl_xor(bidx, off);
        if (ov < best || (ov == best && oi < bidx)) { best = ov; bidx = oi; }
    }
    if (lane == 0) { bestv[w] = best; besti[w] = bidx; }
    __syncthreads();
    if (tid < 2) {
        float v0 = bestv[tid * 2], v1 = bestv[tid * 2 + 1];
        int   i0 = besti[tid * 2], i1 = besti[tid * 2 + 1];
        code_sh[tid] = (v1 < v0 || (v1 == v0 && i1 < i0)) ? i1 : i0;
    }
    __syncthreads();
    const int hh = tid >> 7, d = tid & 127;
    const int code = code_sh[hh];
    const float* cb = hh ? cbv : cbi;
    const float zq = cb[code * 128 + d];
    const float diff = zloc[hh * 128 + d] - zq;
    float sq = diff * diff;
    for (int off = 32; off > 0; off >>= 1) sq += __shfl_xor(sq, off);
    if (lane == 0) wsum2[w] = sq;
    const int s = (set * 2 + hh) * 4 + p;
    ztr[((size_t)bb * 24 + s) * 128 + d] = zq + pos[s * 128 + d];
    __syncthreads();
    if (tid == 0) atomicAdd(&accum[0], wsum2[0] + wsum2[1] + wsum2[2] + wsum2[3]);
}

// ---------------- fused transformer tail: 1024 threads (16 waves) per batch-block ----------------
__global__ __launch_bounds__(1024) void tail_kernel(
    const float* __restrict__ ztr,
    const ushort* __restrict__ aiwbf, const float* __restrict__ aib,
    const ushort* __restrict__ aowbf, const float* __restrict__ aob,
    const float* __restrict__ g1, const float* __restrict__ be1,
    const ushort* __restrict__ l1wbf, const float* __restrict__ l1b,
    const ushort* __restrict__ l2wbf, const float* __restrict__ l2b,
    const float* __restrict__ g2, const float* __restrict__ be2,
    const float* __restrict__ lora_a, float* __restrict__ hbuf)
{
    __shared__ __align__(16) char LDSC[162304];
    float*  Xf  = (float*)LDSC;                    // [24][128] f32 state
    ushort* Abf = (ushort*)(LDSC + 12288);         // [32][136] bf16 A operand
    char*   S   = LDSC + 20992;
    ushort* Wq  = (ushort*)S;                      // 384x136
    float*  QKV = (float*)(S + 104448);            // 24x384
    float*  Ssc = (float*)S;                       // 4x576
    ushort* Wo  = (ushort*)S;                      // 128x136
    float*  psA = (float*)(S + 36864);
    float*  pqA = (float*)(S + 37888);
    float*  muvA= (float*)(S + 38912);
    float*  invA= (float*)(S + 39040);
    ushort* W1  = (ushort*)S;                      // 512x136
    ushort* Hbf = (ushort*)S;                      // 32x520 (stride 520)
    ushort* Wh  = (ushort*)(S + 33280);            // 128x264
    float*  psB = (float*)(S + 100864);
    float*  pqB = (float*)(S + 101888);
    float*  muvB= (float*)(S + 102912);
    float*  invB= (float*)(S + 103040);
    float*  psL = (float*)(S + 103168);

    const int b = blockIdx.x;
    const int tid = threadIdx.x;
    const int w = tid >> 6, lane = tid & 63;
    const int rA = lane & 15, q4 = lane >> 4;

    if (tid < 544) ((uint4*)Abf)[tid] = make_uint4(0u, 0u, 0u, 0u);
    __syncthreads();
    for (int i = tid; i < 3072; i += 1024) {
        float v = ztr[(size_t)b * 3072 + i];
        Xf[i] = v;
        Abf[(i >> 7) * 136 + (i & 127)] = f2bf(v);
    }
    for (int i = tid; i < 6144; i += 1024) {
        const int row = i >> 4, c = i & 15;
        *(uint4*)(Wq + row * 136 + c * 8) = *(const uint4*)(aiwbf + row * 128 + c * 8);
    }
    __syncthreads();

    {
        floatx4 acc[3];
        int mI[3], nI[3];
        for (int i = 0; i < 3; ++i) {
            const int t = w + 16 * i;
            mI[i] = t / 24; nI[i] = t % 24;
            acc[i] = (floatx4)(0.f);
        }
        for (int ks = 0; ks < 4; ++ks) {
            const int k0 = ks * 32 + q4 * 8;
            for (int i = 0; i < 3; ++i) {
                short8 a = *(const short8*)(Abf + (mI[i] * 16 + rA) * 136 + k0);
                short8 bf = *(const short8*)(Wq + (nI[i] * 16 + rA) * 136 + k0);
                acc[i] = __builtin_amdgcn_mfma_f32_16x16x32_bf16(a, bf, acc[i], 0, 0, 0);
            }
        }
        for (int i = 0; i < 3; ++i) {
            const int col = nI[i] * 16 + rA;
            const float bs = aib[col];
            for (int r = 0; r < 4; ++r) {
                const int row = mI[i] * 16 + q4 * 4 + r;
                if (row < 24) QKV[row * 384 + col] = acc[i][r] + bs;
            }
        }
    }
    __syncthreads();

    for (int it = 0; it < 3; ++it) {
        const int e = it * 1024 + tid;
        if (e < 2304) {
            const int h = e / 576, rem = e % 576, i = rem / 24, j = rem % 24;
            float s = 0.f;
            for (int d = 0; d < 32; ++d)
                s += QKV[i * 384 + h * 32 + d] * QKV[j * 384 + 128 + h * 32 + d];
            Ssc[h * 576 + i * 24 + j] = s * 0.17677669529663687f;
        }
    }
    __syncthreads();
    if (tid < 96) {
        const int h = tid / 24, r = tid % 24;
        float* row = Ssc + h * 576 + r * 24;
        float m = row[0];
        for (int j = 1; j < 24; ++j) m = row[j] > m ? row[j] : m;
        float ssum = 0.f;
        for (int j = 0; j < 24; ++j) { float e = __expf(row[j] - m); row[j] = e; ssum += e; }
        float iv = 1.f / ssum;
        for (int j = 0; j < 24; ++j) row[j] *= iv;
    }
    __syncthreads();
    for (int it = 0; it < 3; ++it) {
        const int idx = it * 1024 + tid;
        const int s = idx >> 7, dcol = idx & 127, h = dcol >> 5, d = dcol & 31;
        if (s < 24) {
            float a = 0.f;
            for (int j = 0; j < 24; ++j)
                a += Ssc[h * 576 + s * 24 + j] * QKV[j * 384 + 256 + h * 32 + d];
            Abf[s * 136 + dcol] = f2bf(a);
        }
    }
    __syncthreads();

    for (int i = tid; i < 2048; i += 1024) {
        const int row = i >> 4, c = i & 15;
        *(uint4*)(Wo + row * 136 + c * 8) = *(const uint4*)(aowbf + row * 128 + c * 8);
    }
    __syncthreads();

    {
        const int m = w & 1, n = w >> 1;
        floatx4 acc = (floatx4)(0.f);
        for (int ks = 0; ks < 4; ++ks) {
            const int k0 = ks * 32 + q4 * 8;
            short8 a = *(const short8*)(Abf + (m * 16 + rA) * 136 + k0);
            short8 bf = *(const short8*)(Wo + (n * 16 + rA) * 136 + k0);
            acc = __builtin_amdgcn_mfma_f32_16x16x32_bf16(a, bf, acc, 0, 0, 0);
        }
        const int col = n * 16 + rA;
        const float bs = aob[col];
        for (int r = 0; r < 4; ++r) {
            const int row = m * 16 + q4 * 4 + r;
            acc[r] += bs + (row < 24 ? Xf[row * 128 + col] : 0.f);
        }
        for (int r = 0; r < 4; ++r) {
            float s = acc[r], sq = acc[r] * acc[r];
            for (int off = 1; off < 16; off <<= 1) { s += __shfl_xor(s, off); sq += __shfl_xor(sq, off); }
            if (rA == 0) {
                const int rl = m * 16 + q4 * 4 + r;
                psA[rl * 8 + n] = s; pqA[rl * 8 + n] = sq;
            }
        }
        __syncthreads();
        if (tid < 32) {
            float s = 0.f, sq = 0.f;
            for (int j = 0; j < 8; ++j) { s += psA[tid * 8 + j]; sq += pqA[tid * 8 + j]; }
            float mu = s * (1.f / 128.f);
            float var = sq * (1.f / 128.f) - mu * mu;
            muvA[tid] = mu; invA[tid] = rsqrtf(var + 1e-5f);
        }
        __syncthreads();
        const float gg = g1[col], bb2 = be1[col];
        for (int r = 0; r < 4; ++r) {
            const int rl = m * 16 + q4 * 4 + r;
            if (rl < 24) {
                float v = (acc[r] - muvA[rl]) * invA[rl] * gg + bb2;
                Xf[rl * 128 + col] = v;
                Abf[rl * 136 + col] = f2bf(v);
            }
        }
    }
    __syncthreads();

    for (int i = tid; i < 8192; i += 1024) {
        const int row = i >> 4, c = i & 15;
        *(uint4*)(W1 + row * 136 + c * 8) = *(const uint4*)(l1wbf + row * 128 + c * 8);
    }
    __syncthreads();

    {
        const int m = w & 1, n0b = w >> 1;
        floatx4 acc[4];
        for (int i = 0; i < 4; ++i) acc[i] = (floatx4)(0.f);
        for (int ks = 0; ks < 4; ++ks) {
            const int k0 = ks * 32 + q4 * 8;
            short8 a = *(const short8*)(Abf + (m * 16 + rA) * 136 + k0);
            for (int i = 0; i < 4; ++i) {
                const int n = n0b + i * 8;
                short8 bf = *(const short8*)(W1 + (n * 16 + rA) * 136 + k0);
                acc[i] = __builtin_amdgcn_mfma_f32_16x16x32_bf16(a, bf, acc[i], 0, 0, 0);
            }
        }
        __syncthreads();
        for (int i = 0; i < 4; ++i) {
            const int col = (n0b + i * 8) * 16 + rA;
            const float bs = l1b[col];
            for (int r = 0; r < 4; ++r) {
                const int row = m * 16 + q4 * 4 + r;
                if (row < 24) {
                    float v = acc[i][r] + bs;
                    Hbf[row * 520 + col] = f2bf(v > 0.f ? v : 0.f);
                }
            }
        }
    }
    __syncthreads();

    {
        const int m = w & 1, n = w >> 1;
        floatx4 acc = (floatx4)(0.f);
        for (int kh = 0; kh < 2; ++kh) {
            if (kh) __syncthreads();
            for (int i = tid; i < 4096; i += 1024) {
                const int row = i >> 5, c = i & 31;
                *(uint4*)(Wh + row * 264 + c * 8) =
                    *(const uint4*)(l2wbf + row * 512 + kh * 256 + c * 8);
            }
            __syncthreads();
            for (int ks = 0; ks < 8; ++ks) {
                const int k0 = ks * 32 + q4 * 8;
                short8 a = *(const short8*)(Hbf + (m * 16 + rA) * 520 + kh * 256 + k0);
                short8 bf = *(const short8*)(Wh + (n * 16 + rA) * 264 + k0);
                acc = __builtin_amdgcn_mfma_f32_16x16x32_bf16(a, bf, acc, 0, 0, 0);
            }
        }
        const int col = n * 16 + rA;
        const float bs = l2b[col];
        for (int r = 0; r < 4; ++r) {
            const int row = m * 16 + q4 * 4 + r;
            acc[r] += bs + (row < 24 ? Xf[row * 128 + col] : 0.f);
        }
        for (int r = 0; r < 4; ++r) {
            float s = acc[r], sq = acc[r] * acc[r];
            for (int off = 1; off < 16; off <<= 1) { s += __shfl_xor(s, off); sq += __shfl_xor(sq, off); }
            if (rA == 0) {
                const int rl = m * 16 + q4 * 4 + r;
                psB[rl * 8 + n] = s; pqB[rl * 8 + n] = sq;
            }
        }
        __syncthreads();
        if (tid < 32) {
            float s = 0.f, sq = 0.f;
            for (int j = 0; j < 8; ++j) { s += psB[tid * 8 + j]; sq += pqB[tid * 8 + j]; }
            float mu = s * (1.f / 128.f);
            float var = sq * (1.f / 128.f) - mu * mu;
            muvB[tid] = mu; invB[tid] = rsqrtf(var + 1e-5f);
        }
        __syncthreads();
        const float gg = g2[col], bb2 = be2[col];
        for (int r = 0; r < 4; ++r) {
            const int rl = m * 16 + q4 * 4 + r;
            if (rl < 24)
                Xf[rl * 128 + col] = (acc[r] - muvB[rl]) * invB[rl] * gg + bb2;
        }
    }
    __syncthreads();

    {
        const int r = w & 7, seg = w >> 3;
        float a = 0.f;
        for (int k = 0; k < 24; ++k) {
            const int idx = seg * 1536 + k * 64 + lane;
            a += lora_a[(size_t)r * 3072 + idx] * Xf[idx];
        }
        for (int off = 32; off > 0; off >>= 1) a += __shfl_xor(a, off);
        if (lane == 0) psL[r * 2 + seg] = a;
        __syncthreads();
        if (tid < 8) hbuf[b * 8 + tid] = psL[tid * 2] + psL[tid * 2 + 1];
    }
}

// ---------------- logits: barrier-free inner loop ----------------
__global__ __launch_bounds__(256) void logits_kernel(
    const float* __restrict__ hbuf, const float* __restrict__ lora_b,
    const int* __restrict__ tokc, float* __restrict__ accum, float* __restrict__ out)
{
    const int tid = threadIdx.x;
    const int tcb = blockIdx.x;
    const int w = tid >> 6, lane = tid & 63;
    __shared__ float hl[256];
    __shared__ float slsum[32][4];
    __shared__ float ltokL[32];
    __shared__ int   tvL[32];
    hl[tid] = hbuf[tid];
    if (tid < 32) tvL[tid] = tokc[tid * 2048 + tcb];
    float wr[4][8];
    for (int i = 0; i < 4; ++i) {
        const int vidx = w * 256 + i * 64 + lane;
        const float4* pw = (const float4*)(lora_b + ((size_t)tcb * 1024 + vidx) * 8);
        float4 x = pw[0], y = pw[1];
        wr[i][0] = x.x; wr[i][1] = x.y; wr[i][2] = x.z; wr[i][3] = x.w;
        wr[i][4] = y.x; wr[i][5] = y.y; wr[i][6] = y.z; wr[i][7] = y.w;
    }
    __syncthreads();
    for (int bb = 0; bb < 32; ++bb) {
        const int tv = tvL[bb];
        const float* h = hl + bb * 8;
        float h0 = h[0], h1 = h[1], h2 = h[2], h3 = h[3];
        float h4 = h[4], h5 = h[5], h6 = h[6], h7 = h[7];
        float sl = 0.f;
        for (int i = 0; i < 4; ++i) {
            float lg = h0 * wr[i][0] + h1 * wr[i][1] + h2 * wr[i][2] + h3 * wr[i][3]
                     + h4 * wr[i][4] + h5 * wr[i][5] + h6 * wr[i][6] + h7 * wr[i][7];
            sl += __expf(lg);
            if (w * 256 + i * 64 + lane == tv) ltokL[bb] = lg;   // single writer per bb
        }
        for (int off = 32; off > 0; off >>= 1) sl += __shfl_xor(sl, off);
        if (lane == 0) slsum[bb][w] = sl;                        // per-(bb,w) slot, wave-sync
    }
    __syncthreads();
    float nll = 0.f;
    if (tid < 32)
        nll = logf(slsum[tid][0] + slsum[tid][1] + slsum[tid][2] + slsum[tid][3]) - ltokL[tid];
    if (tid < 64) {
        for (int off = 32; off > 0; off >>= 1) nll += __shfl_xor(nll, off);
        if (tid == 0) {
            atomicAdd(&accum[1], nll);
            __threadfence();
            unsigned int prev = atomicAdd((unsigned int*)(accum + 2), 1u);
            if (prev == 2047u) {
                float vq  = atomicAdd(&accum[0], 0.f);
                float rec = atomicAdd(&accum[1], 0.f);
                out[0] = rec * (1.f / 65536.f) + 0.05f * vq * (1.f / 16384.f);
            }
        }
    }
}

// ---------------- host ----------------
extern "C" void kernel_launch(void* const* d_in, const int* in_sizes, int n_in,
                              void* d_out, int out_size, void* d_ws, size_t ws_size,
                              hipStream_t stream) {
    const int*   tp   = (const int*)d_in[0];
    const int*   tcu  = (const int*)d_in[1];
    const int*   tn   = (const int*)d_in[2];
    const float* emb  = (const float*)d_in[3];
    const float* w1   = (const float*)d_in[4];
    const float* b1   = (const float*)d_in[5];
    const float* w2   = (const float*)d_in[6];
    const float* b2   = (const float*)d_in[7];
    const float* cbi  = (const float*)d_in[8];
    const float* cbv  = (const float*)d_in[9];
    const float* pos  = (const float*)d_in[10];
    const float* aiw  = (const float*)d_in[11];
    const float* aib  = (const float*)d_in[12];
    const float* aow  = (const float*)d_in[13];
    const float* aob  = (const float*)d_in[14];
    const float* g1   = (const float*)d_in[15];
    const float* be1  = (const float*)d_in[16];
    const float* l1w  = (const float*)d_in[17];
    const float* l1b  = (const float*)d_in[18];
    const float* l2w  = (const float*)d_in[19];
    const float* l2b  = (const float*)d_in[20];
    const float* g2   = (const float*)d_in[21];
    const float* be2  = (const float*)d_in[22];
    const float* lra  = (const float*)d_in[23];
    const float* lrb  = (const float*)d_in[24];

    char* wsb = (char*)d_ws;
    ushort* ebf  = (ushort*)(wsb + 0);            // 262144 B
    ushort* w1bf = (ushort*)(wsb + 262144);       // 3145728 B
    ushort* w2bf = (ushort*)(wsb + 3407872);      // 262144 B
    float*  cbiT = (float*)(wsb + 3670016);       // 262144 B
    float*  cbvT = (float*)(wsb + 3932160);       // 262144 B
    ushort* y1   = (ushort*)(wsb + 4194304);      // 25165824 B
    float*  y2   = (float*)(wsb + 29360128);      // 393216 B
    float*  ztr  = (float*)(wsb + 29753344);      // 393216 B
    float*  hbuf = (float*)(wsb + 30146560);      // 1024 B
    float*  accum= (float*)(wsb + 30147584);      // 64 B
    ushort* aiwbf= (ushort*)(wsb + 30147648);     // 98304 B
    ushort* aowbf= (ushort*)(wsb + 30245952);     // 32768 B
    ushort* l1wbf= (ushort*)(wsb + 30278720);     // 131072 B
    ushort* l2wbf= (ushort*)(wsb + 30409792);     // 131072 B -> 30540864
    if (ws_size < 30540864) return;

    prep_all<<<4416, 256, 0, stream>>>(emb, w1, w2, cbi, cbv, aiw, aow, l1w, l2w,
                                       ebf, w1bf, w2bf, cbiT, cbvT,
                                       aiwbf, aowbf, l1wbf, l2wbf, accum);
    conv1_mfma<<<1536, 512, 0, stream>>>(tp, tcu, tn, ebf, w1bf, b1, y1);
    conv2_mfma<<<384, 512, 0, stream>>>(y1, w2bf, b2, y2);
    vq_kernel<<<384, 256, 0, stream>>>(y2, cbiT, cbvT, cbi, cbv, pos, ztr, accum);
    tail_kernel<<<32, 1024, 0, stream>>>(ztr, aiwbf, aib, aowbf, aob, g1, be1,
                                         l1wbf, l1b, l2wbf, l2b, g2, be2, lra, hbuf);
    logits_kernel<<<2048, 256, 0, stream>>>(hbuf, lrb, tcu, accum, (float*)d_out);
}